// Round 8
// baseline (352.174 us; speedup 1.0000x reference)
//
#include <hip/hip_runtime.h>
#include <hip/hip_bf16.h>
#include <hip/hip_cooperative_groups.h>

namespace cg = cooperative_groups;

typedef __attribute__((ext_vector_type(8))) short bf16x8;
typedef __attribute__((ext_vector_type(16))) float f32x16;
typedef __attribute__((ext_vector_type(2))) unsigned u32x2;

// packed f32x2 -> bf16x2 (RNE)
__device__ __forceinline__ unsigned pk2(float a, float b) {
    union { __hip_bfloat162 h2; unsigned u; } c;
    c.h2 = __float22bfloat162_rn(make_float2(a, b));
    return c.u;
}

// async global->LDS DMA, 16 B/lane; LDS dest = wave-uniform base + lane*16
__device__ __forceinline__ void gld16(const void* g, void* l) {
    __builtin_amdgcn_global_load_lds(
        (const __attribute__((address_space(1))) unsigned*)g,
        (__attribute__((address_space(3))) unsigned*)l, 16, 0, 0);
}

// exact transcription of the reference _hilbert_index_to_xy; returns p = x*d + y
__device__ inline int hilbert_p(int index, int d) {
    int x = 0, y = 0;
    for (int s = 1; s < d; s <<= 1) {
        int rx = (index >> 1) & 1;
        int ry = (index ^ rx) & 1;
        if (ry == 0) {
            if (rx == 1) {
                int nx = s - 1 - y;
                int ny = s - 1 - x;
                x = nx; y = ny;
            }
            int t = x; x = y; y = t;
        }
        x += s * rx;
        y += s * ry;
        index >>= 2;
    }
    return x * d + y;
}

// ---- tile geometry decode (tile index 0..1119) ----
struct TileGeo { int g, h, segrow, dgrid, kt; };
__device__ __forceinline__ TileGeo tile_decode(int b) {
    TileGeo t;
    int g, rb;
    if (b < 640)      { g = 0; rb = b; }
    else if (b < 960) { g = 1; rb = b - 640; }
    else              { g = 2; rb = b - 960; }
    const int nseg = 4 >> g;
    const int hl   = rb / (nseg * 32);
    const int r2   = rb - hl * (nseg * 32);
    t.g      = g;
    t.h      = g * 5 + hl;
    t.kt     = r2 & 31;
    t.segrow = (r2 >> 5) * (2048 << g);
    t.dgrid  = (g == 2) ? 128 : 64;
    return t;
}

// ---- gather work items (chunk-linear R6/R7 layouts, unchanged) ----
// K item i in [0, 1120*512): (tile, key j, dim-octet c8) -> one bf16x8 store.
__device__ __forceinline__ void k_item(int i, const float* __restrict__ K,
                                       short* __restrict__ Kp) {
    const int tile = i >> 9, idx = i & 511;
    const int j = idx >> 3, c8 = idx & 7;
    const TileGeo t = tile_decode(tile);
    const int ii = t.kt * 64 + j;
    const int p  = (t.g == 0) ? ii : hilbert_p(ii << t.g, t.dgrid);
    const float* kp = K + ((size_t)((t.segrow + p) * 16 + t.h)) * 64 + c8 * 8;
    float4 k0 = ((const float4*)kp)[0];
    float4 k1 = ((const float4*)kp)[1];
    union { unsigned u4[4]; bf16x8 v; } ck;
    ck.u4[0] = pk2(k0.x, k0.y); ck.u4[1] = pk2(k0.z, k0.w);
    ck.u4[2] = pk2(k1.x, k1.y); ck.u4[3] = pk2(k1.z, k1.w);
    const int kchunk = ((j >> 5) * 4 + (c8 >> 1)) * 64 + (c8 & 1) * 32 + (j & 31);
    *(bf16x8*)&Kp[(size_t)tile * 4096 + kchunk * 8] = ck.v;
}

// V item i in [0, 1120*512): (tile, key-octet k8, dim dd). Consecutive i ->
// consecutive dd, so a wave's 64 lanes read 256 B coalesced per row; the
// bf16 pack of key-pairs IS the transpose. One bf16x8 store per item.
__device__ __forceinline__ void v_item(int i, const float* __restrict__ V,
                                       short* __restrict__ Vp) {
    const int tile = i >> 9, idx = i & 511;
    const int k8 = idx >> 6, dd = idx & 63;
    const TileGeo t = tile_decode(tile);
    float rv[8];
#pragma unroll
    for (int u = 0; u < 8; ++u) {
        const int ii = t.kt * 64 + k8 * 8 + u;
        const int p  = (t.g == 0) ? ii : hilbert_p(ii << t.g, t.dgrid);
        rv[u] = V[((size_t)((t.segrow + p) * 16 + t.h)) * 64 + dd];
    }
    union { unsigned u4[4]; bf16x8 v; } o;
    o.u4[0] = pk2(rv[0], rv[1]); o.u4[1] = pk2(rv[2], rv[3]);
    o.u4[2] = pk2(rv[4], rv[5]); o.u4[3] = pk2(rv[6], rv[7]);
    const int vchunk = ((k8 >> 1) * 2 + (dd >> 5)) * 64 + (k8 & 1) * 32 + (dd & 31);
    *(bf16x8*)&Vp[(size_t)tile * 4096 + vchunk * 8] = o.v;
}

// ---- attn body (R6/R7, UNCHANGED): 32x32x16 MFMA, in-register P via
// cvt_pk + permlane32_swap, dbuf LDS K/V pipeline, counted vmcnt(4),
// 2 barriers/tile, zero bank conflicts. Called with grid = 960 blocks.
__device__ __forceinline__ void attn_body(
    const float* __restrict__ Q, float* __restrict__ O,
    const short* __restrict__ Kp, const short* __restrict__ Vp)
{
    __shared__ __align__(16) short ldsK[2][4096];  // 2 x 8 KB, chunk-linear
    __shared__ __align__(16) short ldsV[2][4096];  // 2 x 8 KB, chunk-linear

    const int bx = blockIdx.x;
    const int g  = bx / 320;
    const int r  = bx - g * 320;
    const int hl = r >> 6;
    const int qb = r & 63;
    const int h  = g * 5 + hl;
    const int qglob = qb * 128;
    const int seg   = qb >> (4 + g);
    const int tile0 = ((g == 0) ? 0 : (g == 1) ? 640 : 960) + (hl * (4 >> g) + seg) * 32;

    const int tid  = threadIdx.x;
    const int wave = tid >> 6;
    const int lane = tid & 63;
    const int l31  = lane & 31;
    const int hi   = lane >> 5;

    // head 15 belongs to no group: zero it here (d_out is poisoned each run).
    if (g == 0 && hl == 0) {
        const float4 z = make_float4(0.f, 0.f, 0.f, 0.f);
        for (int i = tid; i < 2048; i += 256) {
            int row = qglob + (i >> 4);
            ((float4*)O)[(size_t)(row * 16 + 15) * 16 + (i & 15)] = z;
        }
    }

    // ---- Q fragments (B-operand of S^T = K.Q^T, 32x32x16)
    const float cs = 0.125f * 1.44269504088896f;   // scale * log2(e)
    bf16x8 qf[4];
    {
        const int qrow = qglob + wave * 32 + l31;
        const float* qp = Q + ((size_t)(qrow * 16 + h)) * 64;
#pragma unroll
        for (int ks = 0; ks < 4; ++ks) {
            const float4* p4 = (const float4*)(qp + ks * 16 + hi * 8);
            float4 a = p4[0], b = p4[1];
            union { unsigned u[4]; bf16x8 v; } f;
            f.u[0] = pk2(a.x * cs, a.y * cs); f.u[1] = pk2(a.z * cs, a.w * cs);
            f.u[2] = pk2(b.x * cs, b.y * cs); f.u[3] = pk2(b.z * cs, b.w * cs);
            qf[ks] = f.v;
        }
    }

    f32x16 oacc[2];
#pragma unroll
    for (int rr = 0; rr < 16; ++rr) { oacc[0][rr] = 0.f; oacc[1][rr] = 0.f; }
    float lp = 0.f;

    const int lbase = lane * 8;   // fragment base in shorts (lane*16 B)

    // ---- prologue: stage tile 0 into buffer 0
    {
        const size_t tb = (size_t)tile0 << 13;   // 8 KB per tile
        const char* kgp = (const char*)Kp + tb + (wave << 11) + (lane << 4);
        const char* vgp = (const char*)Vp + tb + (wave << 11) + (lane << 4);
        char* klp = (char*)&ldsK[0][0] + (wave << 11);
        char* vlp = (char*)&ldsV[0][0] + (wave << 11);
        gld16(kgp,        klp);
        gld16(kgp + 1024, klp + 1024);
        gld16(vgp,        vlp);
        gld16(vgp + 1024, vlp + 1024);
    }

    for (int kt = 0; kt < 32; ++kt) {
        const int cur = kt & 1;
        if (kt < 31) {
            const size_t tb = (size_t)(tile0 + kt + 1) << 13;
            const char* kgp = (const char*)Kp + tb + (wave << 11) + (lane << 4);
            const char* vgp = (const char*)Vp + tb + (wave << 11) + (lane << 4);
            char* klp = (char*)&ldsK[cur ^ 1][0] + (wave << 11);
            char* vlp = (char*)&ldsV[cur ^ 1][0] + (wave << 11);
            gld16(kgp,        klp);
            gld16(kgp + 1024, klp + 1024);
            gld16(vgp,        vlp);
            gld16(vgp + 1024, vlp + 1024);
            asm volatile("s_waitcnt vmcnt(4)" ::: "memory");
        } else {
            asm volatile("s_waitcnt vmcnt(0)" ::: "memory");
        }
        asm volatile("s_barrier" ::: "memory");   // current tile visible to all waves

        const short* lK = &ldsK[cur][lbase];
        const short* lV = &ldsV[cur][lbase];

        // ---- S-phase: S^T = K.Q^T, exp2, pack. m(reg,hi)=(reg&3)+8*(reg>>2)+4*hi
        float lacc = 0.f;
        unsigned dw[16];   // dw[ks*4 + j*2 + hT]
        __builtin_amdgcn_s_setprio(1);
#pragma unroll
        for (int kb = 0; kb < 2; ++kb) {
            bf16x8 kf0 = *(const bf16x8*)&lK[(kb * 4 + 0) * 512];
            bf16x8 kf1 = *(const bf16x8*)&lK[(kb * 4 + 1) * 512];
            bf16x8 kf2 = *(const bf16x8*)&lK[(kb * 4 + 2) * 512];
            bf16x8 kf3 = *(const bf16x8*)&lK[(kb * 4 + 3) * 512];
            f32x16 sa;
#pragma unroll
            for (int rr = 0; rr < 16; ++rr) sa[rr] = 0.f;
            sa = __builtin_amdgcn_mfma_f32_32x32x16_bf16(kf0, qf[0], sa, 0, 0, 0);
            sa = __builtin_amdgcn_mfma_f32_32x32x16_bf16(kf1, qf[1], sa, 0, 0, 0);
            sa = __builtin_amdgcn_mfma_f32_32x32x16_bf16(kf2, qf[2], sa, 0, 0, 0);
            sa = __builtin_amdgcn_mfma_f32_32x32x16_bf16(kf3, qf[3], sa, 0, 0, 0);
            float pe[16];
#pragma unroll
            for (int rr = 0; rr < 16; ++rr) pe[rr] = __builtin_amdgcn_exp2f(sa[rr]);
            lacc += (((pe[0] + pe[1]) + (pe[2] + pe[3])) + ((pe[4] + pe[5]) + (pe[6] + pe[7])))
                  + (((pe[8] + pe[9]) + (pe[10] + pe[11])) + ((pe[12] + pe[13]) + (pe[14] + pe[15])));
#pragma unroll
            for (int kslo = 0; kslo < 2; ++kslo)
#pragma unroll
                for (int j = 0; j < 2; ++j)
#pragma unroll
                    for (int hT = 0; hT < 2; ++hT) {
                        const int r0 = 2 * j + 8 * kslo + 4 * hT;
                        dw[(kb * 2 + kslo) * 4 + j * 2 + hT] = pk2(pe[r0], pe[r0 + 1]);
                    }
        }
        __builtin_amdgcn_s_setprio(0);
        lp += lacc;

        // ---- assemble PV A-frags via permlane32_swap
        bf16x8 pa[4];
#pragma unroll
        for (int ks = 0; ks < 4; ++ks) {
            u32x2 r0 = __builtin_amdgcn_permlane32_swap(dw[ks * 4 + 0], dw[ks * 4 + 1], false, false);
            u32x2 r1 = __builtin_amdgcn_permlane32_swap(dw[ks * 4 + 2], dw[ks * 4 + 3], false, false);
            union { unsigned u[4]; bf16x8 v; } p;
            p.u[0] = r0[0]; p.u[1] = r1[0]; p.u[2] = r0[1]; p.u[3] = r1[1];
            pa[ks] = p.v;
        }

        __builtin_amdgcn_sched_barrier(0);   // keep vf out of kf/sa live range

        bf16x8 vf[4][2];
#pragma unroll
        for (int ks = 0; ks < 4; ++ks)
#pragma unroll
            for (int db = 0; db < 2; ++db)
                vf[ks][db] = *(const bf16x8*)&lV[(ks * 2 + db) * 512];

        __builtin_amdgcn_s_setprio(1);
#pragma unroll
        for (int ks = 0; ks < 4; ++ks) {
            oacc[0] = __builtin_amdgcn_mfma_f32_32x32x16_bf16(pa[ks], vf[ks][0], oacc[0], 0, 0, 0);
            oacc[1] = __builtin_amdgcn_mfma_f32_32x32x16_bf16(pa[ks], vf[ks][1], oacc[1], 0, 0, 0);
        }
        __builtin_amdgcn_s_setprio(0);

        asm volatile("s_barrier" ::: "memory");   // buf[cur] reads done before overwrite
    }

    float ltot = lp + __shfl_xor(lp, 32, 64);
    float linv = 1.0f / ltot;

#pragma unroll
    for (int rr = 0; rr < 16; ++rr) {
        const int m = (rr & 3) + ((rr >> 2) << 3) + (hi << 2);
        float inv = __shfl(linv, m, 64);
        const int qrow = qglob + wave * 32 + m;
        float* op = O + ((size_t)(qrow * 16 + h)) * 64 + l31;
        op[0]  = oacc[0][rr] * inv;
        op[32] = oacc[1][rr] * inv;
    }
}

// ---- R8: single cooperative kernel: gather -> grid sync -> attn.
// Removes the second launch + the full gather->attn pipeline drain, and makes
// the combined duration directly visible in rocprof (splits kernel time from
// harness aux overhead). Co-residency: 960 blocks, LDS 32 KB, VGPR<=128,
// __launch_bounds__(256,4) -> 4 blocks/CU -> capacity 1024 >= 960.
__global__ __launch_bounds__(256, 4) void fused_kernel(
    const float* __restrict__ Q, float* __restrict__ O,
    const float* __restrict__ K, const float* __restrict__ V,
    short* __restrict__ Kp, short* __restrict__ Vp)
{
    const int gt   = blockIdx.x * 256 + threadIdx.x;
    const int step = gridDim.x * 256;
    for (int i = gt; i < 1120 * 512; i += step) k_item(i, K, Kp);
    for (int i = gt; i < 1120 * 512; i += step) v_item(i, V, Vp);
    __threadfence();                 // device-scope: Kp/Vp visible across XCDs
    cg::this_grid().sync();
    attn_body(Q, O, Kp, Vp);
}

// ---- fallback pair (used only if cooperative launch is rejected) ----
__global__ __launch_bounds__(256, 4) void gather_kv(
    const float* __restrict__ K, const float* __restrict__ V,
    short* __restrict__ Kp, short* __restrict__ Vp)
{
    const int gt   = blockIdx.x * 256 + threadIdx.x;
    const int step = gridDim.x * 256;
    for (int i = gt; i < 1120 * 512; i += step) k_item(i, K, Kp);
    for (int i = gt; i < 1120 * 512; i += step) v_item(i, V, Vp);
}

__global__ __launch_bounds__(256, 4) void attn_kernel(
    const float* __restrict__ Q, float* __restrict__ O,
    const short* __restrict__ Kp, const short* __restrict__ Vp)
{
    attn_body(Q, O, Kp, Vp);
}

extern "C" void kernel_launch(void* const* d_in, const int* in_sizes, int n_in,
                              void* d_out, int out_size, void* d_ws, size_t ws_size,
                              hipStream_t stream) {
    const float* q = (const float*)d_in[0];
    const float* k = (const float*)d_in[1];
    const float* v = (const float*)d_in[2];
    float* out = (float*)d_out;
    short* Kp = (short*)d_ws;                       // 1120 tiles * 8 KB = 9.18 MB
    short* Vp = Kp + (size_t)1120 * 4096;           // + 9.18 MB  (ws total ~18.4 MB)

    void* args[] = { (void*)&q, (void*)&out, (void*)&k, (void*)&v,
                     (void*)&Kp, (void*)&Vp };
    hipError_t e = hipLaunchCooperativeKernel(
        (const void*)fused_kernel, dim3(960), dim3(256), args, 0, stream);
    if (e != hipSuccess) {
        // cooperative launch unsupported here: fall back to two dispatches
        gather_kv<<<960, 256, 0, stream>>>(k, v, Kp, Vp);
        attn_kernel<<<960, 256, 0, stream>>>(q, out, Kp, Vp);
    }
}

// Round 9
// 209.201 us; speedup vs baseline: 1.6834x; 1.6834x over previous
//
#include <hip/hip_runtime.h>
#include <hip/hip_bf16.h>

typedef __attribute__((ext_vector_type(8))) short bf16x8;
typedef __attribute__((ext_vector_type(16))) float f32x16;
typedef __attribute__((ext_vector_type(2))) unsigned u32x2;

// packed f32x2 -> bf16x2 (RNE)
__device__ __forceinline__ unsigned pk2(float a, float b) {
    union { __hip_bfloat162 h2; unsigned u; } c;
    c.h2 = __float22bfloat162_rn(make_float2(a, b));
    return c.u;
}

// async global->LDS DMA, 16 B/lane; LDS dest = wave-uniform base + lane*16
__device__ __forceinline__ void gld16(const void* g, void* l) {
    __builtin_amdgcn_global_load_lds(
        (const __attribute__((address_space(1))) unsigned*)g,
        (__attribute__((address_space(3))) unsigned*)l, 16, 0, 0);
}

// exact transcription of the reference _hilbert_index_to_xy; returns p = x*d + y
__device__ inline int hilbert_p(int index, int d) {
    int x = 0, y = 0;
    for (int s = 1; s < d; s <<= 1) {
        int rx = (index >> 1) & 1;
        int ry = (index ^ rx) & 1;
        if (ry == 0) {
            if (rx == 1) {
                int nx = s - 1 - y;
                int ny = s - 1 - x;
                x = nx; y = ny;
            }
            int t = x; x = y; y = t;
        }
        x += s * rx;
        y += s * ry;
        index >>= 2;
    }
    return x * d + y;
}

// ---- tile geometry decode (tile index 0..1119) ----
struct TileGeo { int g, h, segrow, dgrid, kt; };
__device__ __forceinline__ TileGeo tile_decode(int b) {
    TileGeo t;
    int g, rb;
    if (b < 640)      { g = 0; rb = b; }
    else if (b < 960) { g = 1; rb = b - 640; }
    else              { g = 2; rb = b - 960; }
    const int nseg = 4 >> g;
    const int hl   = rb / (nseg * 32);
    const int r2   = rb - hl * (nseg * 32);
    t.g      = g;
    t.h      = g * 5 + hl;
    t.kt     = r2 & 31;
    t.segrow = (r2 >> 5) * (2048 << g);
    t.dgrid  = (g == 2) ? 128 : 64;
    return t;
}

// ---- gather (measured ~8 us total; R8 pinned it — NOT the bottleneck).
// Chunk-linear layouts (R6..R8, unchanged):
//   kchunk(j,c8)  = ((j>>5)*4 + (c8>>1))*64 + (c8&1)*32 + (j&31)
//   vchunk(dd,k8) = ((k8>>1)*2 + (dd>>5))*64 + (k8&1)*32 + (dd&31)
__device__ __forceinline__ void k_item(int i, const float* __restrict__ K,
                                       short* __restrict__ Kp) {
    const int tile = i >> 9, idx = i & 511;
    const int j = idx >> 3, c8 = idx & 7;
    const TileGeo t = tile_decode(tile);
    const int ii = t.kt * 64 + j;
    const int p  = (t.g == 0) ? ii : hilbert_p(ii << t.g, t.dgrid);
    const float* kp = K + ((size_t)((t.segrow + p) * 16 + t.h)) * 64 + c8 * 8;
    float4 k0 = ((const float4*)kp)[0];
    float4 k1 = ((const float4*)kp)[1];
    union { unsigned u4[4]; bf16x8 v; } ck;
    ck.u4[0] = pk2(k0.x, k0.y); ck.u4[1] = pk2(k0.z, k0.w);
    ck.u4[2] = pk2(k1.x, k1.y); ck.u4[3] = pk2(k1.z, k1.w);
    const int kchunk = ((j >> 5) * 4 + (c8 >> 1)) * 64 + (c8 & 1) * 32 + (j & 31);
    *(bf16x8*)&Kp[(size_t)tile * 4096 + kchunk * 8] = ck.v;
}

__device__ __forceinline__ void v_item(int i, const float* __restrict__ V,
                                       short* __restrict__ Vp) {
    const int tile = i >> 9, idx = i & 511;
    const int k8 = idx >> 6, dd = idx & 63;
    const TileGeo t = tile_decode(tile);
    float rv[8];
#pragma unroll
    for (int u = 0; u < 8; ++u) {
        const int ii = t.kt * 64 + k8 * 8 + u;
        const int p  = (t.g == 0) ? ii : hilbert_p(ii << t.g, t.dgrid);
        rv[u] = V[((size_t)((t.segrow + p) * 16 + t.h)) * 64 + dd];
    }
    union { unsigned u4[4]; bf16x8 v; } o;
    o.u4[0] = pk2(rv[0], rv[1]); o.u4[1] = pk2(rv[2], rv[3]);
    o.u4[2] = pk2(rv[4], rv[5]); o.u4[3] = pk2(rv[6], rv[7]);
    const int vchunk = ((k8 >> 1) * 2 + (dd >> 5)) * 64 + (k8 & 1) * 32 + (dd & 31);
    *(bf16x8*)&Vp[(size_t)tile * 4096 + vchunk * 8] = o.v;
}

__global__ __launch_bounds__(256, 4) void gather_kv(
    const float* __restrict__ K, const float* __restrict__ V,
    short* __restrict__ Kp, short* __restrict__ Vp)
{
    const int gt   = blockIdx.x * 256 + threadIdx.x;
    const int step = gridDim.x * 256;
    for (int i = gt; i < 1120 * 512; i += step) k_item(i, K, Kp);
    for (int i = gt; i < 1120 * 512; i += step) v_item(i, V, Vp);
}

// One block = (group g, head hl, 128-query tile). 4 waves, 32 queries/wave.
// R9: SINGLE-BARRIER pipeline. R8's fusion experiment pinned the harness
// overhead at ~97 us and gather at ~8 us — attn's 102 us is the only lever.
// Counters (MfmaUtil 26 / VALU 43 / ~30% dead) say sync/latency, so:
//  - DMA issue moved to AFTER the top barrier: the barrier then proves all
//    waves' reads of the target buffer (prev iteration) completed, making
//    the old bottom barrier redundant -> 1 barrier/tile instead of 2.
//  - vmcnt(0) before the barrier: only this wave's 4 DMAs (issued a full
//    compute phase ago) are outstanding.
//  - constant zero f32x16 fed directly as MFMA C-in (D != C is legal):
//    kills the per-tile 32 accumulator-init v_movs.
// Everything else unchanged from R6-R8: 32x32x16 MFMA, in-register P via
// cvt_pk + permlane32_swap, dbuf LDS, chunk-linear layouts, 0 bank conflicts.
__global__ __launch_bounds__(256, 4) void attn_kernel(
    const float* __restrict__ Q, float* __restrict__ O,
    const short* __restrict__ Kp, const short* __restrict__ Vp)
{
    __shared__ __align__(16) short ldsK[2][4096];  // 2 x 8 KB, chunk-linear
    __shared__ __align__(16) short ldsV[2][4096];  // 2 x 8 KB, chunk-linear

    const int bx = blockIdx.x;
    const int g  = bx / 320;
    const int r  = bx - g * 320;
    const int hl = r >> 6;
    const int qb = r & 63;
    const int h  = g * 5 + hl;
    const int qglob = qb * 128;
    const int seg   = qb >> (4 + g);
    const int tile0 = ((g == 0) ? 0 : (g == 1) ? 640 : 960) + (hl * (4 >> g) + seg) * 32;

    const int tid  = threadIdx.x;
    const int wave = tid >> 6;
    const int lane = tid & 63;
    const int l31  = lane & 31;
    const int hi   = lane >> 5;

    // head 15 belongs to no group: zero it here (d_out is poisoned each run).
    if (g == 0 && hl == 0) {
        const float4 z = make_float4(0.f, 0.f, 0.f, 0.f);
        for (int i = tid; i < 2048; i += 256) {
            int row = qglob + (i >> 4);
            ((float4*)O)[(size_t)(row * 16 + 15) * 16 + (i & 15)] = z;
        }
    }

    // ---- Q fragments (B-operand of S^T = K.Q^T, 32x32x16)
    const float cs = 0.125f * 1.44269504088896f;   // scale * log2(e)
    bf16x8 qf[4];
    {
        const int qrow = qglob + wave * 32 + l31;
        const float* qp = Q + ((size_t)(qrow * 16 + h)) * 64;
#pragma unroll
        for (int ks = 0; ks < 4; ++ks) {
            const float4* p4 = (const float4*)(qp + ks * 16 + hi * 8);
            float4 a = p4[0], b = p4[1];
            union { unsigned u[4]; bf16x8 v; } f;
            f.u[0] = pk2(a.x * cs, a.y * cs); f.u[1] = pk2(a.z * cs, a.w * cs);
            f.u[2] = pk2(b.x * cs, b.y * cs); f.u[3] = pk2(b.z * cs, b.w * cs);
            qf[ks] = f.v;
        }
    }

    // constant zero accumulator: used as C-in for the first S MFMA of each
    // kb (no per-tile mov-init) and to init oacc.
    f32x16 z16;
#pragma unroll
    for (int rr = 0; rr < 16; ++rr) z16[rr] = 0.f;

    f32x16 oacc[2];
    oacc[0] = z16; oacc[1] = z16;
    float lp = 0.f;

    const int lbase = lane * 8;   // fragment base in shorts (lane*16 B)

    // ---- prologue: stage tile 0 into buffer 0
    {
        const size_t tb = (size_t)tile0 << 13;   // 8 KB per tile
        const char* kgp = (const char*)Kp + tb + (wave << 11) + (lane << 4);
        const char* vgp = (const char*)Vp + tb + (wave << 11) + (lane << 4);
        char* klp = (char*)&ldsK[0][0] + (wave << 11);
        char* vlp = (char*)&ldsV[0][0] + (wave << 11);
        gld16(kgp,        klp);
        gld16(kgp + 1024, klp + 1024);
        gld16(vgp,        vlp);
        gld16(vgp + 1024, vlp + 1024);
    }

    for (int kt = 0; kt < 32; ++kt) {
        const int cur = kt & 1;

        // ---- wait own DMAs (issued a full compute phase ago), then ONE
        // barrier: after it, (a) tile kt is fully staged by all waves,
        // (b) all waves' reads of buf[cur^1] (iteration kt-1) are done,
        // so the next-tile DMAs below cannot race them.
        asm volatile("s_waitcnt vmcnt(0)" ::: "memory");
        asm volatile("s_barrier" ::: "memory");

        if (kt < 31) {
            const size_t tb = (size_t)(tile0 + kt + 1) << 13;
            const char* kgp = (const char*)Kp + tb + (wave << 11) + (lane << 4);
            const char* vgp = (const char*)Vp + tb + (wave << 11) + (lane << 4);
            char* klp = (char*)&ldsK[cur ^ 1][0] + (wave << 11);
            char* vlp = (char*)&ldsV[cur ^ 1][0] + (wave << 11);
            gld16(kgp,        klp);
            gld16(kgp + 1024, klp + 1024);
            gld16(vgp,        vlp);
            gld16(vgp + 1024, vlp + 1024);
        }

        const short* lK = &ldsK[cur][lbase];
        const short* lV = &ldsV[cur][lbase];

        // ---- S-phase: S^T = K.Q^T, exp2, pack. m(reg,hi)=(reg&3)+8*(reg>>2)+4*hi
        float lacc = 0.f;
        unsigned dw[16];   // dw[ks*4 + j*2 + hT]
        __builtin_amdgcn_s_setprio(1);
#pragma unroll
        for (int kb = 0; kb < 2; ++kb) {
            bf16x8 kf0 = *(const bf16x8*)&lK[(kb * 4 + 0) * 512];
            bf16x8 kf1 = *(const bf16x8*)&lK[(kb * 4 + 1) * 512];
            bf16x8 kf2 = *(const bf16x8*)&lK[(kb * 4 + 2) * 512];
            bf16x8 kf3 = *(const bf16x8*)&lK[(kb * 4 + 3) * 512];
            f32x16 sa;
            sa = __builtin_amdgcn_mfma_f32_32x32x16_bf16(kf0, qf[0], z16, 0, 0, 0);
            sa = __builtin_amdgcn_mfma_f32_32x32x16_bf16(kf1, qf[1], sa, 0, 0, 0);
            sa = __builtin_amdgcn_mfma_f32_32x32x16_bf16(kf2, qf[2], sa, 0, 0, 0);
            sa = __builtin_amdgcn_mfma_f32_32x32x16_bf16(kf3, qf[3], sa, 0, 0, 0);
            float pe[16];
#pragma unroll
            for (int rr = 0; rr < 16; ++rr) pe[rr] = __builtin_amdgcn_exp2f(sa[rr]);
            lacc += (((pe[0] + pe[1]) + (pe[2] + pe[3])) + ((pe[4] + pe[5]) + (pe[6] + pe[7])))
                  + (((pe[8] + pe[9]) + (pe[10] + pe[11])) + ((pe[12] + pe[13]) + (pe[14] + pe[15])));
#pragma unroll
            for (int kslo = 0; kslo < 2; ++kslo)
#pragma unroll
                for (int j = 0; j < 2; ++j)
#pragma unroll
                    for (int hT = 0; hT < 2; ++hT) {
                        const int r0 = 2 * j + 8 * kslo + 4 * hT;
                        dw[(kb * 2 + kslo) * 4 + j * 2 + hT] = pk2(pe[r0], pe[r0 + 1]);
                    }
        }
        __builtin_amdgcn_s_setprio(0);
        lp += lacc;

        // ---- assemble PV A-frags via permlane32_swap
        bf16x8 pa[4];
#pragma unroll
        for (int ks = 0; ks < 4; ++ks) {
            u32x2 r0 = __builtin_amdgcn_permlane32_swap(dw[ks * 4 + 0], dw[ks * 4 + 1], false, false);
            u32x2 r1 = __builtin_amdgcn_permlane32_swap(dw[ks * 4 + 2], dw[ks * 4 + 3], false, false);
            union { unsigned u[4]; bf16x8 v; } p;
            p.u[0] = r0[0]; p.u[1] = r1[0]; p.u[2] = r0[1]; p.u[3] = r1[1];
            pa[ks] = p.v;
        }

        __builtin_amdgcn_sched_barrier(0);   // keep vf out of kf/sa live range

        bf16x8 vf[4][2];
#pragma unroll
        for (int ks = 0; ks < 4; ++ks)
#pragma unroll
            for (int db = 0; db < 2; ++db)
                vf[ks][db] = *(const bf16x8*)&lV[(ks * 2 + db) * 512];

        __builtin_amdgcn_s_setprio(1);
#pragma unroll
        for (int ks = 0; ks < 4; ++ks) {
            oacc[0] = __builtin_amdgcn_mfma_f32_32x32x16_bf16(pa[ks], vf[ks][0], oacc[0], 0, 0, 0);
            oacc[1] = __builtin_amdgcn_mfma_f32_32x32x16_bf16(pa[ks], vf[ks][1], oacc[1], 0, 0, 0);
        }
        __builtin_amdgcn_s_setprio(0);
        // no bottom barrier: next iteration's top barrier orders the
        // buf[cur] overwrite against this iteration's reads.
    }

    float ltot = lp + __shfl_xor(lp, 32, 64);
    float linv = 1.0f / ltot;

#pragma unroll
    for (int rr = 0; rr < 16; ++rr) {
        const int m = (rr & 3) + ((rr >> 2) << 3) + (hi << 2);
        float inv = __shfl(linv, m, 64);
        const int qrow = qglob + wave * 32 + m;
        float* op = O + ((size_t)(qrow * 16 + h)) * 64 + l31;
        op[0]  = oacc[0][rr] * inv;
        op[32] = oacc[1][rr] * inv;
    }
}

extern "C" void kernel_launch(void* const* d_in, const int* in_sizes, int n_in,
                              void* d_out, int out_size, void* d_ws, size_t ws_size,
                              hipStream_t stream) {
    const float* q = (const float*)d_in[0];
    const float* k = (const float*)d_in[1];
    const float* v = (const float*)d_in[2];
    float* out = (float*)d_out;
    short* Kp = (short*)d_ws;                       // 1120 tiles * 8 KB = 9.18 MB
    short* Vp = Kp + (size_t)1120 * 4096;           // + 9.18 MB  (ws total ~18.4 MB)

    gather_kv<<<960, 256, 0, stream>>>(k, v, Kp, Vp);
    attn_kernel<<<960, 256, 0, stream>>>(q, out, Kp, Vp);
}